// Round 10
// baseline (344.766 us; speedup 1.0000x reference)
//
#include <hip/hip_runtime.h>
#include <math.h>

#define NBINS   64
#define GROUPS  16
#define HIDDEN  128
#define EPSF    1e-6f

// B=2, C=16, H=W=1024; 32 images of 1M floats; 32x32 tiles of 32x32 elems.
#define IMG_ELEMS   (1024*1024)
#define F4_PER_ROW  256          // 1024 cols / 4
#define NIMG        32           // B*C
#define NBLK        1024         // fused-kernel grid (4 blocks/CU x 256 CU)

typedef float nfloat4 __attribute__((ext_vector_type(4)));  // builtin-compatible

// ---------------------------------------------------------------------------
// Software grid barrier (all NBLK blocks co-resident by __launch_bounds__).
// Ticket scheme on a counter zeroed each replay by k_zero. __threadfence is
// agent-scope: release makes prior stores visible across XCDs, acquire
// prevents stale reads after the spin.
// ---------------------------------------------------------------------------
__device__ __forceinline__ void grid_barrier(unsigned long long* bar,
                                             unsigned long long target)
{
    __syncthreads();
    if (threadIdx.x == 0) {
        __threadfence();                       // release prior writes
        atomicAdd(bar, 1ULL);
        while (atomicAdd(bar, 0ULL) < target)  // device-scope atomic read
            __builtin_amdgcn_s_sleep(16);
        __threadfence();                       // acquire
    }
    __syncthreads();
}

__global__ void k_zero(unsigned long long* bar)
{
    if (threadIdx.x == 0) atomicExch(bar, 0ULL);
}

// ---------------------------------------------------------------------------
// The entire op in one persistent kernel. NBLK blocks x 256 threads.
// P1 stats (all) | P2 hist (32) | P3 conv1+conv2 (32) | P4 lut+apply (all).
// ---------------------------------------------------------------------------
__global__ __launch_bounds__(256, 4) void k_fused(
        const float* __restrict__ x,
        const float* __restrict__ w1, const float* __restrict__ b1,
        const float* __restrict__ w2, const float* __restrict__ b2,
        const float* __restrict__ w3, const float* __restrict__ b3,
        const float* __restrict__ alpha,
        float* __restrict__ blocksum,   // [NIMG][1024]
        float* __restrict__ pmin,       // [NIMG*32]
        float* __restrict__ pmax,       // [NIMG*32]
        float* __restrict__ gmin, float* __restrict__ gmax,   // [NIMG]
        float* __restrict__ pcdf,       // [2][16][64]
        float* __restrict__ h2,         // [128][64]
        unsigned long long* bar,
        float* __restrict__ out)
{
    const int bid  = blockIdx.x;
    const int t    = threadIdx.x;
    const int lane = t & 63;
    const int wave = t >> 6;

    __shared__ float wmn[4], wmx[4];                 // P1
    __shared__ float s_mn, s_inv;                    // P2
    __shared__ int   whist[4][NBINS];                // P2
    __shared__ float dcdf[GROUPS][NBINS];            // P3
    __shared__ float w1s[4 * GROUPS * 5];            // P3
    __shared__ float w2s[4][5];                      // P3
    __shared__ float partial[4][NBINS];              // P4
    __shared__ float lut_s[NBINS];                   // P4

    // ================= Phase 1: per-chunk stats (all blocks) ===============
    {
        const int bc = bid >> 5;   // image
        const int i  = bid & 31;   // tile row
        const float4* xin = (const float4*)(x + (size_t)bc * IMG_ELEMS);
        const int rowbase = (i * 32) * F4_PER_ROW;

        float s = 0.f, mn = INFINITY, mx = -INFINITY;
        #pragma unroll 4
        for (int r = 0; r < 32; ++r) {
            float4 v = xin[rowbase + r * F4_PER_ROW + t];
            s += (v.x + v.y) + (v.z + v.w);
            mn = fminf(mn, fminf(fminf(v.x, v.y), fminf(v.z, v.w)));
            mx = fmaxf(mx, fmaxf(fmaxf(v.x, v.y), fmaxf(v.z, v.w)));
        }
        s += __shfl_xor(s, 4, 64);
        s += __shfl_xor(s, 2, 64);
        s += __shfl_xor(s, 1, 64);
        if ((t & 7) == 0)
            blocksum[bc * 1024 + i * 32 + (t >> 3)] = s;

        #pragma unroll
        for (int st = 32; st > 0; st >>= 1) {
            mn = fminf(mn, __shfl_xor(mn, st, 64));
            mx = fmaxf(mx, __shfl_xor(mx, st, 64));
        }
        if (lane == 0) { wmn[wave] = mn; wmx[wave] = mx; }
        __syncthreads();
        if (t == 0) {
            pmin[bid] = fminf(fminf(wmn[0], wmn[1]), fminf(wmn[2], wmn[3]));
            pmax[bid] = fmaxf(fmaxf(wmx[0], wmx[1]), fmaxf(wmx[2], wmx[3]));
        }
    }
    grid_barrier(bar, 1ULL * NBLK);

    // ================= Phase 2: minmax finalize + histogram (32 blocks) ====
    if (bid < NIMG) {
        const int bc = bid;
        if (wave == 0) {
            float mn = (lane < 32) ? pmin[bc * 32 + lane] : INFINITY;
            float mx = (lane < 32) ? pmax[bc * 32 + lane] : -INFINITY;
            #pragma unroll
            for (int st = 32; st > 0; st >>= 1) {
                mn = fminf(mn, __shfl_xor(mn, st, 64));
                mx = fmaxf(mx, __shfl_xor(mx, st, 64));
            }
            if (lane == 0) {
                gmin[bc] = mn; gmax[bc] = mx;
                s_mn = mn; s_inv = 1.0f / (mx - mn + EPSF);
            }
        }
        __syncthreads();
        const float mnv = s_mn;
        const float inv = s_inv;

        int idx0, idx1, idx2, idx3;
        {
            const float* bs = blocksum + bc * 1024;
            #define MKIDX(D, IT) { \
                float bmean = bs[t + (IT)*256] * (1.0f / 1024.0f); \
                float xs = (bmean - mnv) * inv; \
                int id = (int)rintf(xs * 63.0f); \
                D = max(0, min(id, 63)); }
            MKIDX(idx0, 0) MKIDX(idx1, 1) MKIDX(idx2, 2) MKIDX(idx3, 3)
            #undef MKIDX
        }
        int cnt = 0;
        #pragma unroll 1
        for (int b = 0; b < NBINS; ++b) {
            int p = __popcll(__ballot(idx0 == b)) + __popcll(__ballot(idx1 == b))
                  + __popcll(__ballot(idx2 == b)) + __popcll(__ballot(idx3 == b));
            cnt += (lane == b) ? p : 0;
        }
        whist[wave][lane] = cnt;
        __syncthreads();
        if (t < NBINS) {
            int h = whist[0][t] + whist[1][t] + whist[2][t] + whist[3][t];
            #pragma unroll
            for (int d = 1; d < 64; d <<= 1) {
                int v = __shfl_up(h, d, 64);
                if (t >= d) h += v;
            }
            pcdf[bc * NBINS + t] = (float)h * (0.5f / (1024.0f + EPSF));
        }
    }
    grid_barrier(bar, 2ULL * NBLK);

    // ================= Phase 3: conv1 + shuffle conv2 (32 blocks) ==========
    if (bid < 32) {
        const int ocb = bid * 4;
        const int ocl = wave >> 0;   // wave-uniform 0..3
        const int k   = lane;

        for (int o = t; o < GROUPS * NBINS; o += 256)
            ((float*)dcdf)[o] = pcdf[o] + pcdf[GROUPS * NBINS + o];
        for (int o = t; o < 4 * GROUPS * 5; o += 256) {
            const int oo  = o / 80;
            const int rem = o - oo * 80;
            const int ic  = rem / 5;
            const int tap = rem - ic * 5;
            w1s[o] = w1[((ocb + oo) * GROUPS + ic) * 25 + 10 + tap];
        }
        if (t < 20) w2s[t / 5][t % 5] = w2[(ocb + t / 5) * 25 + 10 + t % 5];
        __syncthreads();

        float acc = b1[ocb + ocl];
        const float* wrow = w1s + ocl * 80;
        for (int ic = 0; ic < GROUPS; ++ic) {
            #pragma unroll
            for (int tap = 0; tap < 5; ++tap) {
                const int kk = k - 2 + tap;
                if (kk >= 0 && kk < NBINS)
                    acc += wrow[ic * 5 + tap] * dcdf[ic][kk];
            }
        }
        const float c1 = fmaxf(acc, 0.f);
        const float m2 = __shfl_up(c1, 2, 64);
        const float m1 = __shfl_up(c1, 1, 64);
        const float p1 = __shfl_down(c1, 1, 64);
        const float p2 = __shfl_down(c1, 2, 64);
        float a = b2[ocb + ocl];
        a += w2s[ocl][0] * ((k >= 2) ? m2 : 0.f);
        a += w2s[ocl][1] * ((k >= 1) ? m1 : 0.f);
        a += w2s[ocl][2] * c1;
        a += w2s[ocl][3] * ((k <= 62) ? p1 : 0.f);
        a += w2s[ocl][4] * ((k <= 61) ? p2 : 0.f);
        h2[(ocb + ocl) * NBINS + k] = fmaxf(a, 0.f);
    }
    grid_barrier(bar, 3ULL * NBLK);

    // ================= Phase 4: per-block lut finalize + remap (all) =======
    {
        const int img  = bid >> 5;          // 32 blocks per image
        const int c    = img & 15;          // channel == group (C/G == 1)
        const int q    = wave;
        const int k    = lane;

        // conv3 partial: wave q covers h = q*32 .. q*32+31
        {
            float pa = 0.f;
            const float* w3p = w3 + c * HIDDEN + q * 32;
            const float* h2p = h2 + (q * 32) * NBINS + k;
            #pragma unroll 8
            for (int h = 0; h < 32; ++h)
                pa += w3p[h] * h2p[h * NBINS];
            partial[q][k] = pa;
        }
        __syncthreads();
        if (q == 0) {
            float acc = b3[c] + ((partial[0][k] + partial[1][k])
                               + (partial[2][k] + partial[3][k]));
            float d = fmaxf(acc, 0.f) + log1pf(expf(-fabsf(acc)));  // softplus
            #pragma unroll
            for (int dd = 1; dd < 64; dd <<= 1) {
                float v = __shfl_up(d, dd, 64);
                if (k >= dd) d += v;
            }
            const float tot = __shfl(d, 63, 64);
            lut_s[k] = d / (tot + EPSF) + (float)k * (1.0f / 63.0f);
        }
        __syncthreads();

        const float mnv = gmin[img];
        const float mxv = gmax[img];
        const float r   = mxv - mnv;
        const float inv = 1.0f / (r + EPSF);
        const float aa  = 1.0f / (1.0f + expf(-alpha[0]));

        const size_t base4 = (size_t)img * (IMG_ELEMS / 4)
                           + (size_t)(bid & 31) * 8192;   // 2 parts = 8192 f4
        const float4* xin = (const float4*)x;
        nfloat4* o4 = (nfloat4*)out;

        #pragma unroll 2
        for (int it = 0; it < 32; ++it) {
            const size_t f = base4 + (size_t)t + (size_t)it * 256;
            float4 v = xin[f];
            nfloat4 w;
            #define REMAP(DST, SRC) { \
                float x01 = (SRC - mnv) * inv; \
                float pos = x01 * 63.0f; \
                int il = max(0, min((int)floorf(pos), 63)); \
                int ih = min(il + 1, 63); \
                float wt = pos - (float)il; \
                float vlo = lut_s[il], vhi = lut_s[ih]; \
                DST = (aa * fmaf(wt, vhi - vlo, vlo) + (1.0f - aa) * x01) * r + mnv; }
            REMAP(w.x, v.x) REMAP(w.y, v.y) REMAP(w.z, v.z) REMAP(w.w, v.w)
            #undef REMAP
            __builtin_nontemporal_store(w, &o4[f]);
        }
    }
}

// ---------------------------------------------------------------------------
extern "C" void kernel_launch(void* const* d_in, const int* in_sizes, int n_in,
                              void* d_out, int out_size, void* d_ws, size_t ws_size,
                              hipStream_t stream)
{
    const float* x     = (const float*)d_in[0];
    const float* w1    = (const float*)d_in[1];
    const float* b1    = (const float*)d_in[2];
    const float* w2    = (const float*)d_in[3];
    const float* b2    = (const float*)d_in[4];
    const float* w3    = (const float*)d_in[5];
    const float* b3    = (const float*)d_in[6];
    const float* alpha = (const float*)d_in[7];
    float* out = (float*)d_out;

    float* ws = (float*)d_ws;
    float* blocksum = ws;            // 32768
    float* pmin     = ws + 32768;    // 1024
    float* pmax     = ws + 33792;    // 1024
    float* gmin     = ws + 34816;    // 32
    float* gmax     = ws + 34848;    // 32
    float* pcdf     = ws + 34880;    // 2048
    float* h2       = ws + 36928;    // 8192
    unsigned long long* bar = (unsigned long long*)(ws + 45120); // 8B-aligned

    k_zero <<<1,    64,  0, stream>>>(bar);
    k_fused<<<NBLK, 256, 0, stream>>>(x, w1, b1, w2, b2, w3, b3, alpha,
                                      blocksum, pmin, pmax, gmin, gmax,
                                      pcdf, h2, bar, out);
}

// Round 11
// 267.592 us; speedup vs baseline: 1.2884x; 1.2884x over previous
//
#include <hip/hip_runtime.h>
#include <math.h>

#define NBINS   64
#define GROUPS  16
#define HIDDEN  128
#define EPSF    1e-6f

// B=2, C=16, H=W=1024; 32 images of 1M floats; 32x32 tiles of 32x32 elems.
#define IMG_ELEMS   (1024*1024)
#define F4_PER_ROW  256          // 1024 cols / 4
#define NIMG        32           // B*C
#define NBLK        1024         // 4 blocks/CU x 256 CU -> all co-resident

typedef float nfloat4 __attribute__((ext_vector_type(4)));  // builtin-compatible

__device__ __forceinline__ unsigned ld_agent(const unsigned* p)
{
    return __hip_atomic_load(p, __ATOMIC_RELAXED, __HIP_MEMORY_SCOPE_AGENT);
}

// counters zeroed each replay (poison-safe); cnt1 per image on own cacheline
__global__ void k_zero(unsigned* cnt)
{
    for (int o = threadIdx.x; o < 1088; o += 256) cnt[o] = 0u;
}

// ---------------------------------------------------------------------------
// Entire op in one persistent kernel, sync via counters (no RMW spinning):
// P1 stats (all 1024) -> per-image arrive; last arriver of each image is the
// WORKER: P2 hist+minmax, arrive cnt2; spin cnt2==32 (32 spinners, relaxed
// loads); P3 conv1+conv2 (4 channels each), arrive cnt3. Everyone spins
// cnt3==32 (relaxed loads + s_sleep), then P4 lut+remap (all 1024).
// ---------------------------------------------------------------------------
__global__ __launch_bounds__(256, 4) void k_fused(
        const float* __restrict__ x,
        const float* __restrict__ w1, const float* __restrict__ b1,
        const float* __restrict__ w2, const float* __restrict__ b2,
        const float* __restrict__ w3, const float* __restrict__ b3,
        const float* __restrict__ alpha,
        float* __restrict__ blocksum,   // [NIMG][1024]
        float* __restrict__ pmin,       // [NIMG*32]
        float* __restrict__ pmax,       // [NIMG*32]
        float* __restrict__ gmin, float* __restrict__ gmax,   // [NIMG]
        float* __restrict__ pcdf,       // [2][16][64]
        float* __restrict__ h2,         // [128][64]
        unsigned* __restrict__ cnt,     // cnt1: [img*32]; cnt2: [1024]; cnt3: [1056]
        float* __restrict__ out)
{
    const int bid  = blockIdx.x;
    const int t    = threadIdx.x;
    const int lane = t & 63;
    const int wave = t >> 6;
    const int img  = bid >> 5;     // 32 blocks per image
    const int part = bid & 31;

    __shared__ float wmn[4], wmx[4];
    __shared__ unsigned s_old;
    __shared__ float s_mn, s_inv;
    __shared__ int   whist[4][NBINS];
    __shared__ float dcdf[GROUPS][NBINS];
    __shared__ float w1s[4 * GROUPS * 5];
    __shared__ float w2s[4][5];
    __shared__ float partial[4][NBINS];
    __shared__ float lut_s[NBINS];

    // ================= Phase 1: per-chunk stats (all blocks) ===============
    {
        const float4* xin = (const float4*)(x + (size_t)img * IMG_ELEMS);
        const int rowbase = (part * 32) * F4_PER_ROW;

        float s = 0.f, mn = INFINITY, mx = -INFINITY;
        #pragma unroll 4
        for (int r = 0; r < 32; ++r) {
            float4 v = xin[rowbase + r * F4_PER_ROW + t];
            s += (v.x + v.y) + (v.z + v.w);
            mn = fminf(mn, fminf(fminf(v.x, v.y), fminf(v.z, v.w)));
            mx = fmaxf(mx, fmaxf(fmaxf(v.x, v.y), fmaxf(v.z, v.w)));
        }
        s += __shfl_xor(s, 4, 64);
        s += __shfl_xor(s, 2, 64);
        s += __shfl_xor(s, 1, 64);
        if ((t & 7) == 0)
            blocksum[img * 1024 + part * 32 + (t >> 3)] = s;

        #pragma unroll
        for (int st = 32; st > 0; st >>= 1) {
            mn = fminf(mn, __shfl_xor(mn, st, 64));
            mx = fmaxf(mx, __shfl_xor(mx, st, 64));
        }
        if (lane == 0) { wmn[wave] = mn; wmx[wave] = mx; }
        __syncthreads();
        if (t == 0) {
            pmin[bid] = fminf(fminf(wmn[0], wmn[1]), fminf(wmn[2], wmn[3]));
            pmax[bid] = fmaxf(fmaxf(wmx[0], wmx[1]), fmaxf(wmx[2], wmx[3]));
        }
    }

    // arrive on per-image counter; last arriver (old==31) becomes the worker
    __threadfence();                 // release this block's P1 stores
    __syncthreads();
    if (t == 0) s_old = atomicAdd(&cnt[img * 32], 1u);
    __syncthreads();
    const bool worker = (s_old == 31u);

    if (worker) {
        __threadfence();             // acquire: see all 32 blocks' P1 stores
        // ============= Phase 2: minmax finalize + ballot histogram =========
        const int bc = img;
        if (wave == 0) {
            float mn = (lane < 32) ? pmin[bc * 32 + lane] : INFINITY;
            float mx = (lane < 32) ? pmax[bc * 32 + lane] : -INFINITY;
            #pragma unroll
            for (int st = 32; st > 0; st >>= 1) {
                mn = fminf(mn, __shfl_xor(mn, st, 64));
                mx = fmaxf(mx, __shfl_xor(mx, st, 64));
            }
            if (lane == 0) {
                gmin[bc] = mn; gmax[bc] = mx;
                s_mn = mn; s_inv = 1.0f / (mx - mn + EPSF);
            }
        }
        __syncthreads();
        const float mnv = s_mn;
        const float inv = s_inv;

        int idx0, idx1, idx2, idx3;
        {
            const float* bs = blocksum + bc * 1024;
            #define MKIDX(D, IT) { \
                float bmean = bs[t + (IT)*256] * (1.0f / 1024.0f); \
                float xs = (bmean - mnv) * inv; \
                int id = (int)rintf(xs * 63.0f); \
                D = max(0, min(id, 63)); }
            MKIDX(idx0, 0) MKIDX(idx1, 1) MKIDX(idx2, 2) MKIDX(idx3, 3)
            #undef MKIDX
        }
        int cntv = 0;
        #pragma unroll 1
        for (int b = 0; b < NBINS; ++b) {
            int p = __popcll(__ballot(idx0 == b)) + __popcll(__ballot(idx1 == b))
                  + __popcll(__ballot(idx2 == b)) + __popcll(__ballot(idx3 == b));
            cntv += (lane == b) ? p : 0;
        }
        whist[wave][lane] = cntv;
        __syncthreads();
        if (t < NBINS) {
            int h = whist[0][t] + whist[1][t] + whist[2][t] + whist[3][t];
            #pragma unroll
            for (int d = 1; d < 64; d <<= 1) {
                int v = __shfl_up(h, d, 64);
                if (t >= d) h += v;
            }
            pcdf[bc * NBINS + t] = (float)h * (0.5f / (1024.0f + EPSF));
        }

        // arrive cnt2; wait for all 32 workers (relaxed-load spin, 32 spinners)
        __threadfence();
        __syncthreads();
        if (t == 0) {
            atomicAdd(&cnt[1024], 1u);
            while (ld_agent(&cnt[1024]) < 32u) __builtin_amdgcn_s_sleep(4);
        }
        __syncthreads();
        __threadfence();             // acquire pcdf from other workers

        // ============= Phase 3: conv1 + shuffle conv2 (4 channels) =========
        {
            const int ocb = img * 4;
            const int ocl = wave;    // wave-uniform 0..3
            const int k   = lane;

            for (int o = t; o < GROUPS * NBINS; o += 256)
                ((float*)dcdf)[o] = pcdf[o] + pcdf[GROUPS * NBINS + o];
            for (int o = t; o < 4 * GROUPS * 5; o += 256) {
                const int oo  = o / 80;
                const int rem = o - oo * 80;
                const int ic  = rem / 5;
                const int tap = rem - ic * 5;
                w1s[o] = w1[((ocb + oo) * GROUPS + ic) * 25 + 10 + tap];
            }
            if (t < 20) w2s[t / 5][t % 5] = w2[(ocb + t / 5) * 25 + 10 + t % 5];
            __syncthreads();

            float acc = b1[ocb + ocl];
            const float* wrow = w1s + ocl * 80;
            for (int ic = 0; ic < GROUPS; ++ic) {
                #pragma unroll
                for (int tap = 0; tap < 5; ++tap) {
                    const int kk = k - 2 + tap;
                    if (kk >= 0 && kk < NBINS)
                        acc += wrow[ic * 5 + tap] * dcdf[ic][kk];
                }
            }
            const float c1 = fmaxf(acc, 0.f);
            const float m2 = __shfl_up(c1, 2, 64);
            const float m1 = __shfl_up(c1, 1, 64);
            const float p1 = __shfl_down(c1, 1, 64);
            const float p2 = __shfl_down(c1, 2, 64);
            float a = b2[ocb + ocl];
            a += w2s[ocl][0] * ((k >= 2) ? m2 : 0.f);
            a += w2s[ocl][1] * ((k >= 1) ? m1 : 0.f);
            a += w2s[ocl][2] * c1;
            a += w2s[ocl][3] * ((k <= 62) ? p1 : 0.f);
            a += w2s[ocl][4] * ((k <= 61) ? p2 : 0.f);
            h2[(ocb + ocl) * NBINS + k] = fmaxf(a, 0.f);
        }
        __threadfence();
        __syncthreads();
        if (t == 0) atomicAdd(&cnt[1056], 1u);
    }

    // all blocks wait for h2 (relaxed-load spin + sleep; workers done fast)
    if (t == 0) {
        while (ld_agent(&cnt[1056]) < 32u) __builtin_amdgcn_s_sleep(8);
    }
    __syncthreads();
    __threadfence();                 // acquire gmin/gmax/h2

    // ================= Phase 4: per-block lut finalize + remap =============
    {
        const int c = img & 15;      // channel == group (C/G == 1)
        const int q = wave;
        const int k = lane;

        {
            float pa = 0.f;
            const float* w3p = w3 + c * HIDDEN + q * 32;
            const float* h2p = h2 + (q * 32) * NBINS + k;
            #pragma unroll 8
            for (int h = 0; h < 32; ++h)
                pa += w3p[h] * h2p[h * NBINS];
            partial[q][k] = pa;
        }
        __syncthreads();
        if (q == 0) {
            float acc = b3[c] + ((partial[0][k] + partial[1][k])
                               + (partial[2][k] + partial[3][k]));
            float d = fmaxf(acc, 0.f) + log1pf(expf(-fabsf(acc)));  // softplus
            #pragma unroll
            for (int dd = 1; dd < 64; dd <<= 1) {
                float v = __shfl_up(d, dd, 64);
                if (k >= dd) d += v;
            }
            const float tot = __shfl(d, 63, 64);
            lut_s[k] = d / (tot + EPSF) + (float)k * (1.0f / 63.0f);
        }
        __syncthreads();

        const float mnv = gmin[img];
        const float mxv = gmax[img];
        const float r   = mxv - mnv;
        const float inv = 1.0f / (r + EPSF);
        const float aa  = 1.0f / (1.0f + expf(-alpha[0]));

        const size_t base4 = (size_t)img * (IMG_ELEMS / 4)
                           + (size_t)part * 8192;     // 8192 float4 per block
        const float4* xin = (const float4*)x;
        nfloat4* o4 = (nfloat4*)out;

        #pragma unroll 2
        for (int it = 0; it < 32; ++it) {
            const size_t f = base4 + (size_t)t + (size_t)it * 256;
            float4 v = xin[f];
            nfloat4 w;
            #define REMAP(DST, SRC) { \
                float x01 = (SRC - mnv) * inv; \
                float pos = x01 * 63.0f; \
                int il = max(0, min((int)floorf(pos), 63)); \
                int ih = min(il + 1, 63); \
                float wt = pos - (float)il; \
                float vlo = lut_s[il], vhi = lut_s[ih]; \
                DST = (aa * fmaf(wt, vhi - vlo, vlo) + (1.0f - aa) * x01) * r + mnv; }
            REMAP(w.x, v.x) REMAP(w.y, v.y) REMAP(w.z, v.z) REMAP(w.w, v.w)
            #undef REMAP
            __builtin_nontemporal_store(w, &o4[f]);
        }
    }
}

// ---------------------------------------------------------------------------
extern "C" void kernel_launch(void* const* d_in, const int* in_sizes, int n_in,
                              void* d_out, int out_size, void* d_ws, size_t ws_size,
                              hipStream_t stream)
{
    const float* x     = (const float*)d_in[0];
    const float* w1    = (const float*)d_in[1];
    const float* b1    = (const float*)d_in[2];
    const float* w2    = (const float*)d_in[3];
    const float* b2    = (const float*)d_in[4];
    const float* w3    = (const float*)d_in[5];
    const float* b3    = (const float*)d_in[6];
    const float* alpha = (const float*)d_in[7];
    float* out = (float*)d_out;

    float* ws = (float*)d_ws;
    float* blocksum = ws;            // 32768
    float* pmin     = ws + 32768;    // 1024
    float* pmax     = ws + 33792;    // 1024
    float* gmin     = ws + 34816;    // 32
    float* gmax     = ws + 34848;    // 32
    float* pcdf     = ws + 34880;    // 2048
    float* h2       = ws + 36928;    // 8192
    unsigned* cnt   = (unsigned*)(ws + 45120);  // 1088 uints, 128B-aligned

    k_zero <<<1,    256, 0, stream>>>(cnt);
    k_fused<<<NBLK, 256, 0, stream>>>(x, w1, b1, w2, b2, w3, b3, alpha,
                                      blocksum, pmin, pmax, gmin, gmax,
                                      pcdf, h2, cnt, out);
}